// Round 22
// baseline (183.604 us; speedup 1.0000x reference)
//
#include <hip/hip_runtime.h>
#include <hip/hip_bf16.h>

#define B_    32
#define S_    256
#define BS_   8192      // B_*S_
#define Wc_   16        // chars per word
#define CDIM_ 16
#define CH_   16
#define WDIM_ 300
#define KX_   332       // WDIM_+2*CH_
#define XC_   336       // padded X row (84 float4)
#define GEN_  100
#define WVP_  104       // padded word_vecs row
#define WH_   32
#define NG_   128       // 4*WH_
#define GROWS 16        // rows per k_genp block (r22: back to 16 + weight prefetch)

constexpr size_t OFF_WV   = 0;                                   // [8192][104] f32 (unused after fusion)
constexpr size_t OFF_PRE  = OFF_WV   + (size_t)BS_*WVP_;         // [2][256][32][128]
constexpr size_t OFF_LO   = OFF_PRE  + (size_t)2*S_*B_*NG_;      // [8192][64]
constexpr size_t OFF_CHB  = OFF_LO   + (size_t)BS_*64;           // [8192][32] char h
constexpr size_t OFF_GWT  = OFF_CHB  + (size_t)BS_*32;           // [332][128]
constexpr size_t OFF_WIHT = OFF_GWT  + (size_t)KX_*128;          // [2][100][128]
constexpr size_t OFF_WHHT = OFF_WIHT + (size_t)2*GEN_*NG_;       // [2][32][128]
constexpr size_t OFF_OW   = OFF_WHHT + (size_t)2*WH_*NG_;        // [2][64]

typedef __attribute__((ext_vector_type(2))) float f2;
typedef __attribute__((ext_vector_type(2))) unsigned u2;

// native-exp2 activations: v_exp_f32 + v_rcp_f32, ~3 insts vs ~11 for __ocml_expf
__device__ __forceinline__ float sigm(float x){
  return __builtin_amdgcn_rcpf(1.f + __builtin_amdgcn_exp2f(-1.44269504089f*x));
}
__device__ __forceinline__ float tanh_(float x){
  return 1.f - 2.f*__builtin_amdgcn_rcpf(1.f + __builtin_amdgcn_exp2f(2.88539008178f*x));
}
__device__ __forceinline__ float rdlane(float v, int lane){
  return __uint_as_float(__builtin_amdgcn_readlane(__float_as_uint(v), lane));
}
#if defined(__has_builtin) && __has_builtin(__builtin_amdgcn_permlane32_swap)
__device__ __forceinline__ float xswap32(float v, bool lo32){
  u2 r = __builtin_amdgcn_permlane32_swap(__float_as_uint(v), __float_as_uint(v), false, false);
  return __uint_as_float(lo32 ? r.y : r.x);
}
#else
__device__ __forceinline__ float xswap32(float v, bool lo32){
  (void)lo32;
  return __shfl_xor(v, 32);
}
#endif

// ---------------- prep: transpose small weights ----------------
__global__ void k_prep(const float* gen_W, const float* wih_f, const float* wih_b,
                       const float* whh_f, const float* whh_b, const float* out_W,
                       float* ws){
  int idx = blockIdx.x*blockDim.x + threadIdx.x;
  int stride = gridDim.x*blockDim.x;
  for (int i = idx; i < GEN_*KX_; i += stride){       // gen_W [100][332] -> [k][j] stride 128
    int j = i / KX_, k = i - j*KX_;
    ws[OFF_GWT + (size_t)k*128 + j] = gen_W[i];
  }
  for (int i = idx; i < NG_*GEN_; i += stride){       // w_Wih [128][100] -> [k][g]
    int g = i / GEN_, k = i - g*GEN_;
    ws[OFF_WIHT + 0*GEN_*NG_ + (size_t)k*NG_ + g] = wih_f[i];
    ws[OFF_WIHT + 1*GEN_*NG_ + (size_t)k*NG_ + g] = wih_b[i];
  }
  for (int i = idx; i < NG_*WH_; i += stride){        // w_Whh [128][32] -> [k][g]
    int g = i / WH_, k = i - g*WH_;
    ws[OFF_WHHT + 0*WH_*NG_ + (size_t)k*NG_ + g] = whh_f[i];
    ws[OFF_WHHT + 1*WH_*NG_ + (size_t)k*NG_ + g] = whh_b[i];
  }
  for (int i = idx; i < 2*64; i += stride) ws[OFF_OW + i] = out_W[i];
}

// ---------------- char BiLSTM: lane = (seq, unit); 16 lanes/seq ----------------
__global__ void __launch_bounds__(256, 2) k_char(const int* char_ids, const float* char_table,
                       const float* Wih_f, const float* Whh_f, const float* b_f,
                       const float* Wih_b, const float* Whh_b, const float* b_b,
                       float* ws){
  __shared__ float xr[16*324];        // [s][t][k] row stride 20, s stride 324
  __shared__ float occ_pad[4864];     // 19KB: VGPR-budget lever
  const int dir = blockIdx.x & 1;
  const int sg  = blockIdx.x >> 1;
  const int tid = threadIdx.x;
  const float* WI = dir ? Wih_b : Wih_f;
  const float* WH = dir ? Whh_b : Whh_f;
  const float* BB = dir ? b_b  : b_f;
  const int ls = tid >> 4, u = tid & 15;
  const int seq0 = sg * 16;
  {
    const int id = char_ids[(seq0 + ls)*Wc_ + u];
    const float4* sr = (const float4*)(char_table + (size_t)id*CDIM_);
    float4 v0 = sr[0], v1 = sr[1], v2 = sr[2], v3 = sr[3];
    float* xw = &xr[ls*324 + u*20];
    *(float4*)(xw+0)  = v0; *(float4*)(xw+4)  = v1;
    *(float4*)(xw+8)  = v2; *(float4*)(xw+12) = v3;
    if (__builtin_expect(id == 0x7fffffff, 0)) occ_pad[tid] = v0.x;  // unprovable-dead
  }
  float wi[4][16];
  #pragma unroll
  for (int g = 0; g < 4; ++g){
    const float4* wr = (const float4*)(WI + (size_t)(g*16+u)*CDIM_);
    float4 a = wr[0], b = wr[1], c = wr[2], d = wr[3];
    wi[g][0]=a.x; wi[g][1]=a.y; wi[g][2]=a.z; wi[g][3]=a.w;
    wi[g][4]=b.x; wi[g][5]=b.y; wi[g][6]=b.z; wi[g][7]=b.w;
    wi[g][8]=c.x; wi[g][9]=c.y; wi[g][10]=c.z; wi[g][11]=c.w;
    wi[g][12]=d.x; wi[g][13]=d.y; wi[g][14]=d.z; wi[g][15]=d.w;
  }
  float bias[4];
  #pragma unroll
  for (int g = 0; g < 4; ++g) bias[g] = BB[g*16+u];
  __syncthreads();
  float xp[16][4];
  const float* xb = &xr[ls*324];
  #pragma unroll
  for (int p = 0; p < 16; ++p){
    const int tm = dir ? (15-p) : p;
    const float4 x0 = *(const float4*)(xb + tm*20 + 0);
    const float4 x1 = *(const float4*)(xb + tm*20 + 4);
    const float4 x2 = *(const float4*)(xb + tm*20 + 8);
    const float4 x3 = *(const float4*)(xb + tm*20 + 12);
    float xk[16] = {x0.x,x0.y,x0.z,x0.w, x1.x,x1.y,x1.z,x1.w,
                    x2.x,x2.y,x2.z,x2.w, x3.x,x3.y,x3.z,x3.w};
    #pragma unroll
    for (int g = 0; g < 4; ++g){
      float a0 = bias[g], a1 = 0.f;
      #pragma unroll
      for (int k = 0; k < 16; k += 2){ a0 += wi[g][k]*xk[k]; a1 += wi[g][k+1]*xk[k+1]; }
      xp[p][g] = a0 + a1;
    }
  }
  float wh[4][16];
  #pragma unroll
  for (int g = 0; g < 4; ++g){
    const float4* wr = (const float4*)(WH + (size_t)(g*16+u)*CH_);
    float4 a = wr[0], b = wr[1], c = wr[2], d = wr[3];
    wh[g][0]=a.x; wh[g][1]=a.y; wh[g][2]=a.z; wh[g][3]=a.w;
    wh[g][4]=b.x; wh[g][5]=b.y; wh[g][6]=b.z; wh[g][7]=b.w;
    wh[g][8]=c.x; wh[g][9]=c.y; wh[g][10]=c.z; wh[g][11]=c.w;
    wh[g][12]=d.x; wh[g][13]=d.y; wh[g][14]=d.z; wh[g][15]=d.w;
  }
  const int lbase = (tid & 63) & 48;
  float h = 0.f, c = 0.f;
  #pragma unroll
  for (int p = 0; p < 16; ++p){
    float ai = xp[p][0], af = xp[p][1], ag = xp[p][2], ao = xp[p][3];
    #pragma unroll
    for (int k = 0; k < 16; ++k){
      const float hk = __shfl(h, lbase + k, 64);
      ai += wh[0][k]*hk; af += wh[1][k]*hk;
      ag += wh[2][k]*hk; ao += wh[3][k]*hk;
    }
    c = sigm(af)*c + sigm(ai)*tanh_(ag);
    h = sigm(ao)*tanh_(c);
  }
  ws[OFF_CHB + (size_t)(seq0 + ls)*32 + dir*16 + u] = h;
}

// ---------------- fused gen + word-LSTM input projection ----------------
// r22: GROWS=16 (fewest blocks -> least total weight-latency exposure; r21
// showed per-block weight traffic is GROWS-independent, so small GROWS just
// multiplies it) + 1-deep software pipeline on the weight loads: prefetch
// iter k4+1's four weights at the top, compute with current four. 16 rows'
// compute (~64 FMA + 16 LDS b128 ≈ 200cy) covers the ~200cy L2 latency.
// unroll(disable) stays as the r20 unroll-jam guard.
__global__ void __launch_bounds__(128) k_genp(const int* word_ids, const float* word_table, const float* gen_b,
                       const float* wb_f, const float* wb_b, float* ws){
  __shared__ __align__(16) float xt[GROWS*XC_];    // 21.5 KB
  __shared__ __align__(16) float wvs[GROWS*WVP_];  // 6.5 KB
  __shared__ int wids[GROWS];
  const int r0 = blockIdx.x*GROWS;
  if (threadIdx.x < GROWS) wids[threadIdx.x] = word_ids[r0 + threadIdx.x];
  __syncthreads();
  float4* xt4 = (float4*)xt;
  for (int i = threadIdx.x; i < GROWS*75; i += 128){       // word part: 75 float4/row
    const int r = i/75, q = i - r*75;
    xt4[r*84 + q] = ((const float4*)(word_table + (size_t)wids[r]*WDIM_))[q];
  }
  for (int i = threadIdx.x; i < GROWS*8; i += 128){        // char part: 8 float4/row
    const int r = i >> 3, q = i & 7;
    xt4[r*84 + 75 + q] = ((const float4*)(ws + OFF_CHB + (size_t)(r0+r)*32))[q];
  }
  __syncthreads();
  const int j = threadIdx.x;                   // j<100 valid
  const float bj = (j < GEN_) ? gen_b[j] : 0.f;
  float acc[GROWS];
  #pragma unroll
  for (int r = 0; r < GROWS; ++r) acc[r] = bj;
  const float* WT = ws + OFF_GWT;
  float w0c = WT[(size_t)0*128 + j], w1c = WT[(size_t)1*128 + j];
  float w2c = WT[(size_t)2*128 + j], w3c = WT[(size_t)3*128 + j];
  #pragma clang loop unroll(disable)
  for (int k4 = 0; k4 < KX_/4; ++k4){
    const int kn = (k4 + 1 < KX_/4) ? (k4 + 1)*4 : k4*4;   // branchless in-bounds prefetch
    const float w0n = WT[(size_t)(kn+0)*128 + j];
    const float w1n = WT[(size_t)(kn+1)*128 + j];
    const float w2n = WT[(size_t)(kn+2)*128 + j];
    const float w3n = WT[(size_t)(kn+3)*128 + j];
    #pragma unroll
    for (int r = 0; r < GROWS; ++r){
      const float4 xv = xt4[r*84 + k4];
      acc[r] += w0c*xv.x + w1c*xv.y + w2c*xv.z + w3c*xv.w;
    }
    w0c = w0n; w1c = w1n; w2c = w2n; w3c = w3n;
  }
  if (j < GEN_){
    #pragma unroll
    for (int r = 0; r < GROWS; ++r){
      const float a = acc[r];
      wvs[r*WVP_ + j] = 0.5f*a*(1.f + erff(a*0.70710678118f));
    }
  }
  __syncthreads();
  // phase 2: pre-activation projection for both directions
  const int g = threadIdx.x;                   // all 128 valid
  for (int d = 0; d < 2; ++d){
    const float* W2 = ws + OFF_WIHT + (size_t)d*GEN_*NG_;
    const float wb = (d ? wb_b : wb_f)[g];
    float ac2[GROWS];
    #pragma unroll
    for (int r = 0; r < GROWS; ++r) ac2[r] = wb;
    float v0c = W2[(size_t)0*NG_ + g], v1c = W2[(size_t)1*NG_ + g];
    float v2c = W2[(size_t)2*NG_ + g], v3c = W2[(size_t)3*NG_ + g];
    #pragma clang loop unroll(disable)
    for (int k4 = 0; k4 < GEN_/4; ++k4){
      const int kn = (k4 + 1 < GEN_/4) ? (k4 + 1)*4 : k4*4;
      const float v0n = W2[(size_t)(kn+0)*NG_ + g];
      const float v1n = W2[(size_t)(kn+1)*NG_ + g];
      const float v2n = W2[(size_t)(kn+2)*NG_ + g];
      const float v3n = W2[(size_t)(kn+3)*NG_ + g];
      const int k = k4*4;
      #pragma unroll
      for (int r = 0; r < GROWS; ++r){
        const float4 xv = *(const float4*)&wvs[r*WVP_ + k];
        ac2[r] += v0c*xv.x + v1c*xv.y + v2c*xv.z + v3c*xv.w;
      }
      v0c = v0n; v1c = v1n; v2c = v2n; v3c = v3n;
    }
    float* pre = ws + OFF_PRE + (size_t)d*S_*B_*NG_;
    #pragma unroll
    for (int r = 0; r < GROWS; ++r){
      const int row = r0 + r, bb = row >> 8, ss = row & 255;
      pre[((size_t)ss*B_ + bb)*NG_ + g] = ac2[r];
    }
  }
}

// ---------------- word BiLSTM scan: 1 wave per (dir, batch row), packed FMAs ----------------
// (r19 best: 81.5us, VGPR 88, permlane exchange — unchanged this round)
#define BN_ ((size_t)B_*NG_)
__global__ void __launch_bounds__(64) k_wlstm(const float* __restrict__ WHT,
                                              const float* __restrict__ PRE,
                                              float* __restrict__ LO){
  __shared__ __align__(16) float hring[5632];   // [32][36] used; size = VGPR-budget lever (r12)
  const int pair = blockIdx.x;          // 0..63
  const int d = pair >> 5;
  const int n = pair & 31;
  const int l = threadIdx.x;
  const bool lo32 = (l < 32);
  const float* WT = WHT + (size_t)d*WH_*NG_;
  f2 w2[32];                            // (wA[k], wB[k]) — gates l and 64+l
  #pragma unroll
  for (int k = 0; k < 32; ++k){
    w2[k] = (f2){ WT[(size_t)k*NG_ + l], WT[(size_t)k*NG_ + 64 + l] };
  }
  const float* pre = PRE + (size_t)d*S_*BN_ + (size_t)n*NG_;
  const float* p0 = pre + (size_t)(d ? (S_-1) : 0)*BN_;
  const ptrdiff_t stp = (d ? -1 : 1) * (ptrdiff_t)BN_;
  float cst = 0.f, h = 0.f;

  // prefetch steps 0..3
  float a0A = p0[0*stp + l], a0B = p0[0*stp + 64 + l];
  float a1A = p0[1*stp + l], a1B = p0[1*stp + 64 + l];
  float a2A = p0[2*stp + l], a2B = p0[2*stp + 64 + l];
  float a3A = p0[3*stp + l], a3B = p0[3*stp + 64 + l];

#define WSTEP(pAv, pBv, sidx) { \
    f2 q0 = (f2){(pAv),(pBv)}, q1 = (f2){0.f,0.f}, q2 = (f2){0.f,0.f}, q3 = (f2){0.f,0.f}; \
    _Pragma("unroll") \
    for (int k = 0; k < 32; k += 4){ \
      const float h0 = rdlane(h, k+0); \
      const float h1 = rdlane(h, k+1); \
      const float h2 = rdlane(h, k+2); \
      const float h3 = rdlane(h, k+3); \
      q0 += w2[k+0] * (f2){h0,h0}; \
      q1 += w2[k+1] * (f2){h1,h1}; \
      q2 += w2[k+2] * (f2){h2,h2}; \
      q3 += w2[k+3] * (f2){h3,h3}; \
    } \
    const f2 qs = (q0+q1)+(q2+q3); \
    const float aA = qs.x;                  /* lanes<32: i, lanes>=32: f */ \
    const float aB = qs.y;                  /* lanes<32: g, lanes>=32: o */ \
    const float fga = xswap32(aA, lo32);    /* lanes<32 receive f */ \
    const float oga = xswap32(aB, lo32);    /* lanes<32 receive o */ \
    const float cc = sigm(fga)*cst + sigm(aA)*tanh_(aB);  /* valid lanes<32 */ \
    cst = cc; \
    h = sigm(oga)*tanh_(cc);                               /* valid lanes<32 */ \
    if (lo32) hring[((sidx) & 31)*36 + l] = h; \
  }

  for (int t = 0; t < S_; t += 4){
    float n0A=0.f, n0B=0.f, n1A=0.f, n1B=0.f, n2A=0.f, n2B=0.f, n3A=0.f, n3B=0.f;
    if (t + 4 < S_){                     // issue prefetch for steps t+4..t+7 FIRST
      const float* q = p0 + (ptrdiff_t)(t+4)*stp;
      n0A = q[0*stp + l]; n0B = q[0*stp + 64 + l];
      n1A = q[1*stp + l]; n1B = q[1*stp + 64 + l];
      n2A = q[2*stp + l]; n2B = q[2*stp + 64 + l];
      n3A = q[3*stp + l]; n3B = q[3*stp + 64 + l];
    }
    WSTEP(a0A, a0B, t+0)
    WSTEP(a1A, a1B, t+1)
    WSTEP(a2A, a2B, t+2)
    WSTEP(a3A, a3B, t+3)
    a0A=n0A; a0B=n0B; a1A=n1A; a1B=n1B;
    a2A=n2A; a2B=n2B; a3A=n3A; a3B=n3B;

    if ((t & 31) == 28){                 // flush steps s0..s0+31 coalesced
      const int s0 = t & ~31;
      const int srow = l >> 1, half = l & 1;
      const int s = s0 + srow;
      const int ss = d ? (S_ - 1 - s) : s;
      const float4* src = (const float4*)&hring[srow*36 + half*16];
      float4* dst = (float4*)(LO + ((size_t)n*S_ + ss)*64 + d*32 + half*16);
      dst[0] = src[0]; dst[1] = src[1]; dst[2] = src[2]; dst[3] = src[3];
    }
  }
#undef WSTEP
}

// ---------------- output head: sigmoid(lstm_out @ out_W^T + b) -> f32 ----------------
__global__ void k_out(const float* ws, const float* out_b, float* out){
  const int row = blockIdx.x*blockDim.x + threadIdx.x;
  const float4* lo = (const float4*)(ws + OFF_LO + (size_t)row*64);
  const float* OW = ws + OFF_OW;
  float a0 = out_b[0], a1 = out_b[1];
  #pragma unroll
  for (int q = 0; q < 16; ++q){
    const float4 v = lo[q];
    a0 += OW[q*4+0]*v.x + OW[q*4+1]*v.y + OW[q*4+2]*v.z + OW[q*4+3]*v.w;
    a1 += OW[64+q*4+0]*v.x + OW[64+q*4+1]*v.y + OW[64+q*4+2]*v.z + OW[64+q*4+3]*v.w;
  }
  out[row*2+0] = sigm(a0);
  out[row*2+1] = sigm(a1);
}

extern "C" void kernel_launch(void* const* d_in, const int* in_sizes, int n_in,
                              void* d_out, int out_size, void* d_ws, size_t ws_size,
                              hipStream_t stream){
  (void)in_sizes; (void)n_in; (void)out_size; (void)ws_size;
  const int*   word_ids   = (const int*)  d_in[0];
  const int*   char_ids   = (const int*)  d_in[1];
  const float* word_table = (const float*)d_in[2];
  const float* char_table = (const float*)d_in[3];
  const float* c_Wih_f    = (const float*)d_in[4];
  const float* c_Whh_f    = (const float*)d_in[5];
  const float* c_b_f      = (const float*)d_in[6];
  const float* c_Wih_b    = (const float*)d_in[7];
  const float* c_Whh_b    = (const float*)d_in[8];
  const float* c_b_b      = (const float*)d_in[9];
  const float* gen_W      = (const float*)d_in[10];
  const float* gen_b      = (const float*)d_in[11];
  const float* w_Wih_f    = (const float*)d_in[12];
  const float* w_Whh_f    = (const float*)d_in[13];
  const float* w_b_f      = (const float*)d_in[14];
  const float* w_Wih_b    = (const float*)d_in[15];
  const float* w_Whh_b    = (const float*)d_in[16];
  const float* w_b_b      = (const float*)d_in[17];
  const float* out_W      = (const float*)d_in[18];
  const float* out_b      = (const float*)d_in[19];
  float* ws  = (float*)d_ws;
  float* out = (float*)d_out;

  hipLaunchKernelGGL(k_prep,  dim3(64),   dim3(256), 0, stream,
                     gen_W, w_Wih_f, w_Wih_b, w_Whh_f, w_Whh_b, out_W, ws);
  hipLaunchKernelGGL(k_char,  dim3(1024), dim3(256), 0, stream,
                     char_ids, char_table, c_Wih_f, c_Whh_f, c_b_f,
                     c_Wih_b, c_Whh_b, c_b_b, ws);
  hipLaunchKernelGGL(k_genp,  dim3(BS_/GROWS), dim3(128), 0, stream,
                     word_ids, word_table, gen_b, w_b_f, w_b_b, ws);
  hipLaunchKernelGGL(k_wlstm, dim3(64),   dim3(64),  0, stream,
                     ws + OFF_WHHT, ws + OFF_PRE, ws + OFF_LO);
  hipLaunchKernelGGL(k_out,   dim3(64),   dim3(128), 0, stream, ws, out_b, out);
}

// Round 23
// 173.435 us; speedup vs baseline: 1.0586x; 1.0586x over previous
//
#include <hip/hip_runtime.h>
#include <hip/hip_bf16.h>

#define B_    32
#define S_    256
#define BS_   8192      // B_*S_
#define Wc_   16        // chars per word
#define CDIM_ 16
#define CH_   16
#define WDIM_ 300
#define KX_   332       // WDIM_+2*CH_
#define XC_   336       // padded X row (84 float4)
#define GEN_  100
#define WVP_  104       // padded word_vecs row
#define WH_   32
#define NG_   128       // 4*WH_
#define GROWS 8         // rows per k_genp block (best: r21 config)

constexpr size_t OFF_WV   = 0;                                   // [8192][104] f32 (unused after fusion)
constexpr size_t OFF_PRE  = OFF_WV   + (size_t)BS_*WVP_;         // [2][256][32][128]
constexpr size_t OFF_LO   = OFF_PRE  + (size_t)2*S_*B_*NG_;      // [8192][64]
constexpr size_t OFF_CHB  = OFF_LO   + (size_t)BS_*64;           // [8192][32] char h
constexpr size_t OFF_GWT  = OFF_CHB  + (size_t)BS_*32;           // [332][128]
constexpr size_t OFF_WIHT = OFF_GWT  + (size_t)KX_*128;          // [2][100][128]
constexpr size_t OFF_WHHT = OFF_WIHT + (size_t)2*GEN_*NG_;       // [2][32][128]
constexpr size_t OFF_OW   = OFF_WHHT + (size_t)2*WH_*NG_;        // [2][64]

typedef __attribute__((ext_vector_type(2))) float f2;
typedef __attribute__((ext_vector_type(2))) unsigned u2;

// native-exp2 activations: v_exp_f32 + v_rcp_f32, ~3 insts vs ~11 for __ocml_expf
__device__ __forceinline__ float sigm(float x){
  return __builtin_amdgcn_rcpf(1.f + __builtin_amdgcn_exp2f(-1.44269504089f*x));
}
__device__ __forceinline__ float tanh_(float x){
  return 1.f - 2.f*__builtin_amdgcn_rcpf(1.f + __builtin_amdgcn_exp2f(2.88539008178f*x));
}
__device__ __forceinline__ float rdlane(float v, int lane){
  return __uint_as_float(__builtin_amdgcn_readlane(__float_as_uint(v), lane));
}
#if defined(__has_builtin) && __has_builtin(__builtin_amdgcn_permlane32_swap)
__device__ __forceinline__ float xswap32(float v, bool lo32){
  u2 r = __builtin_amdgcn_permlane32_swap(__float_as_uint(v), __float_as_uint(v), false, false);
  return __uint_as_float(lo32 ? r.y : r.x);
}
#else
__device__ __forceinline__ float xswap32(float v, bool lo32){
  (void)lo32;
  return __shfl_xor(v, 32);
}
#endif

// ---------------- prep: transpose small weights ----------------
__global__ void k_prep(const float* gen_W, const float* wih_f, const float* wih_b,
                       const float* whh_f, const float* whh_b, const float* out_W,
                       float* ws){
  int idx = blockIdx.x*blockDim.x + threadIdx.x;
  int stride = gridDim.x*blockDim.x;
  for (int i = idx; i < GEN_*KX_; i += stride){       // gen_W [100][332] -> [k][j] stride 128
    int j = i / KX_, k = i - j*KX_;
    ws[OFF_GWT + (size_t)k*128 + j] = gen_W[i];
  }
  for (int i = idx; i < NG_*GEN_; i += stride){       // w_Wih [128][100] -> [k][g]
    int g = i / GEN_, k = i - g*GEN_;
    ws[OFF_WIHT + 0*GEN_*NG_ + (size_t)k*NG_ + g] = wih_f[i];
    ws[OFF_WIHT + 1*GEN_*NG_ + (size_t)k*NG_ + g] = wih_b[i];
  }
  for (int i = idx; i < NG_*WH_; i += stride){        // w_Whh [128][32] -> [k][g]
    int g = i / WH_, k = i - g*WH_;
    ws[OFF_WHHT + 0*WH_*NG_ + (size_t)k*NG_ + g] = whh_f[i];
    ws[OFF_WHHT + 1*WH_*NG_ + (size_t)k*NG_ + g] = whh_b[i];
  }
  for (int i = idx; i < 2*64; i += stride) ws[OFF_OW + i] = out_W[i];
}

// ---------------- char BiLSTM: lane = (seq, unit); 16 lanes/seq ----------------
__global__ void __launch_bounds__(256, 2) k_char(const int* char_ids, const float* char_table,
                       const float* Wih_f, const float* Whh_f, const float* b_f,
                       const float* Wih_b, const float* Whh_b, const float* b_b,
                       float* ws){
  __shared__ float xr[16*324];        // [s][t][k] row stride 20, s stride 324
  __shared__ float occ_pad[4864];     // 19KB: VGPR-budget lever
  const int dir = blockIdx.x & 1;
  const int sg  = blockIdx.x >> 1;
  const int tid = threadIdx.x;
  const float* WI = dir ? Wih_b : Wih_f;
  const float* WH = dir ? Whh_b : Whh_f;
  const float* BB = dir ? b_b  : b_f;
  const int ls = tid >> 4, u = tid & 15;
  const int seq0 = sg * 16;
  {
    const int id = char_ids[(seq0 + ls)*Wc_ + u];
    const float4* sr = (const float4*)(char_table + (size_t)id*CDIM_);
    float4 v0 = sr[0], v1 = sr[1], v2 = sr[2], v3 = sr[3];
    float* xw = &xr[ls*324 + u*20];
    *(float4*)(xw+0)  = v0; *(float4*)(xw+4)  = v1;
    *(float4*)(xw+8)  = v2; *(float4*)(xw+12) = v3;
    if (__builtin_expect(id == 0x7fffffff, 0)) occ_pad[tid] = v0.x;  // unprovable-dead
  }
  float wi[4][16];
  #pragma unroll
  for (int g = 0; g < 4; ++g){
    const float4* wr = (const float4*)(WI + (size_t)(g*16+u)*CDIM_);
    float4 a = wr[0], b = wr[1], c = wr[2], d = wr[3];
    wi[g][0]=a.x; wi[g][1]=a.y; wi[g][2]=a.z; wi[g][3]=a.w;
    wi[g][4]=b.x; wi[g][5]=b.y; wi[g][6]=b.z; wi[g][7]=b.w;
    wi[g][8]=c.x; wi[g][9]=c.y; wi[g][10]=c.z; wi[g][11]=c.w;
    wi[g][12]=d.x; wi[g][13]=d.y; wi[g][14]=d.z; wi[g][15]=d.w;
  }
  float bias[4];
  #pragma unroll
  for (int g = 0; g < 4; ++g) bias[g] = BB[g*16+u];
  __syncthreads();
  float xp[16][4];
  const float* xb = &xr[ls*324];
  #pragma unroll
  for (int p = 0; p < 16; ++p){
    const int tm = dir ? (15-p) : p;
    const float4 x0 = *(const float4*)(xb + tm*20 + 0);
    const float4 x1 = *(const float4*)(xb + tm*20 + 4);
    const float4 x2 = *(const float4*)(xb + tm*20 + 8);
    const float4 x3 = *(const float4*)(xb + tm*20 + 12);
    float xk[16] = {x0.x,x0.y,x0.z,x0.w, x1.x,x1.y,x1.z,x1.w,
                    x2.x,x2.y,x2.z,x2.w, x3.x,x3.y,x3.z,x3.w};
    #pragma unroll
    for (int g = 0; g < 4; ++g){
      float a0 = bias[g], a1 = 0.f;
      #pragma unroll
      for (int k = 0; k < 16; k += 2){ a0 += wi[g][k]*xk[k]; a1 += wi[g][k+1]*xk[k+1]; }
      xp[p][g] = a0 + a1;
    }
  }
  float wh[4][16];
  #pragma unroll
  for (int g = 0; g < 4; ++g){
    const float4* wr = (const float4*)(WH + (size_t)(g*16+u)*CH_);
    float4 a = wr[0], b = wr[1], c = wr[2], d = wr[3];
    wh[g][0]=a.x; wh[g][1]=a.y; wh[g][2]=a.z; wh[g][3]=a.w;
    wh[g][4]=b.x; wh[g][5]=b.y; wh[g][6]=b.z; wh[g][7]=b.w;
    wh[g][8]=c.x; wh[g][9]=c.y; wh[g][10]=c.z; wh[g][11]=c.w;
    wh[g][12]=d.x; wh[g][13]=d.y; wh[g][14]=d.z; wh[g][15]=d.w;
  }
  const int lbase = (tid & 63) & 48;
  float h = 0.f, c = 0.f;
  #pragma unroll
  for (int p = 0; p < 16; ++p){
    float ai = xp[p][0], af = xp[p][1], ag = xp[p][2], ao = xp[p][3];
    #pragma unroll
    for (int k = 0; k < 16; ++k){
      const float hk = __shfl(h, lbase + k, 64);
      ai += wh[0][k]*hk; af += wh[1][k]*hk;
      ag += wh[2][k]*hk; ao += wh[3][k]*hk;
    }
    c = sigm(af)*c + sigm(ai)*tanh_(ag);
    h = sigm(ao)*tanh_(c);
  }
  ws[OFF_CHB + (size_t)(seq0 + ls)*32 + dir*16 + u] = h;
}

// ---------------- fused gen + word-LSTM input projection ----------------
// Best config (r21): GROWS=8 (grid 1024, 4 blocks/CU -> 8 waves/CU) +
// unroll(disable) on the k4 weight loops (r20's GROWS=4 unroll-jammed to
// VGPR 256 + 206MB spill traffic). r22's weight-prefetch variant was null-
// to-negative; reverted.
__global__ void __launch_bounds__(128) k_genp(const int* word_ids, const float* word_table, const float* gen_b,
                       const float* wb_f, const float* wb_b, float* ws){
  __shared__ __align__(16) float xt[GROWS*XC_];    // 10.8 KB
  __shared__ __align__(16) float wvs[GROWS*WVP_];  // 3.3 KB
  __shared__ int wids[GROWS];
  const int r0 = blockIdx.x*GROWS;
  if (threadIdx.x < GROWS) wids[threadIdx.x] = word_ids[r0 + threadIdx.x];
  __syncthreads();
  float4* xt4 = (float4*)xt;
  for (int i = threadIdx.x; i < GROWS*75; i += 128){       // word part: 75 float4/row
    const int r = i/75, q = i - r*75;
    xt4[r*84 + q] = ((const float4*)(word_table + (size_t)wids[r]*WDIM_))[q];
  }
  for (int i = threadIdx.x; i < GROWS*8; i += 128){        // char part: 8 float4/row
    const int r = i >> 3, q = i & 7;
    xt4[r*84 + 75 + q] = ((const float4*)(ws + OFF_CHB + (size_t)(r0+r)*32))[q];
  }
  __syncthreads();
  const int j = threadIdx.x;                   // j<100 valid
  const float bj = (j < GEN_) ? gen_b[j] : 0.f;
  float acc[GROWS];
  #pragma unroll
  for (int r = 0; r < GROWS; ++r) acc[r] = bj;
  const float* WT = ws + OFF_GWT;
  #pragma clang loop unroll(disable)
  for (int k4 = 0; k4 < KX_/4; ++k4){
    const int k = k4*4;
    const float w0 = WT[(size_t)(k+0)*128 + j];
    const float w1 = WT[(size_t)(k+1)*128 + j];
    const float w2 = WT[(size_t)(k+2)*128 + j];
    const float w3 = WT[(size_t)(k+3)*128 + j];
    #pragma unroll
    for (int r = 0; r < GROWS; ++r){
      const float4 xv = xt4[r*84 + k4];
      acc[r] += w0*xv.x + w1*xv.y + w2*xv.z + w3*xv.w;
    }
  }
  if (j < GEN_){
    #pragma unroll
    for (int r = 0; r < GROWS; ++r){
      const float a = acc[r];
      wvs[r*WVP_ + j] = 0.5f*a*(1.f + erff(a*0.70710678118f));
    }
  }
  __syncthreads();
  // phase 2: pre-activation projection for both directions
  const int g = threadIdx.x;                   // all 128 valid
  for (int d = 0; d < 2; ++d){
    const float* W2 = ws + OFF_WIHT + (size_t)d*GEN_*NG_;
    const float wb = (d ? wb_b : wb_f)[g];
    float ac2[GROWS];
    #pragma unroll
    for (int r = 0; r < GROWS; ++r) ac2[r] = wb;
    #pragma clang loop unroll(disable)
    for (int k4 = 0; k4 < GEN_/4; ++k4){
      const int k = k4*4;
      const float w0 = W2[(size_t)(k+0)*NG_ + g];
      const float w1 = W2[(size_t)(k+1)*NG_ + g];
      const float w2 = W2[(size_t)(k+2)*NG_ + g];
      const float w3 = W2[(size_t)(k+3)*NG_ + g];
      #pragma unroll
      for (int r = 0; r < GROWS; ++r){
        const float4 xv = *(const float4*)&wvs[r*WVP_ + k];
        ac2[r] += w0*xv.x + w1*xv.y + w2*xv.z + w3*xv.w;
      }
    }
    float* pre = ws + OFF_PRE + (size_t)d*S_*B_*NG_;
    #pragma unroll
    for (int r = 0; r < GROWS; ++r){
      const int row = r0 + r, bb = row >> 8, ss = row & 255;
      pre[((size_t)ss*B_ + bb)*NG_ + g] = ac2[r];
    }
  }
}

// ---------------- word BiLSTM scan: 1 wave per (dir, batch row), packed FMAs ----------------
// (best: 81.4us, VGPR 88, pk_fma + permlane exchange + LDS h-ring + 22.5KB
// VGPR-budget lever. 10 rounds of further attempts all <2% — lone-wave
// stall floor at source level.)
#define BN_ ((size_t)B_*NG_)
__global__ void __launch_bounds__(64) k_wlstm(const float* __restrict__ WHT,
                                              const float* __restrict__ PRE,
                                              float* __restrict__ LO){
  __shared__ __align__(16) float hring[5632];   // [32][36] used; size = VGPR-budget lever (r12)
  const int pair = blockIdx.x;          // 0..63
  const int d = pair >> 5;
  const int n = pair & 31;
  const int l = threadIdx.x;
  const bool lo32 = (l < 32);
  const float* WT = WHT + (size_t)d*WH_*NG_;
  f2 w2[32];                            // (wA[k], wB[k]) — gates l and 64+l
  #pragma unroll
  for (int k = 0; k < 32; ++k){
    w2[k] = (f2){ WT[(size_t)k*NG_ + l], WT[(size_t)k*NG_ + 64 + l] };
  }
  const float* pre = PRE + (size_t)d*S_*BN_ + (size_t)n*NG_;
  const float* p0 = pre + (size_t)(d ? (S_-1) : 0)*BN_;
  const ptrdiff_t stp = (d ? -1 : 1) * (ptrdiff_t)BN_;
  float cst = 0.f, h = 0.f;

  // prefetch steps 0..3
  float a0A = p0[0*stp + l], a0B = p0[0*stp + 64 + l];
  float a1A = p0[1*stp + l], a1B = p0[1*stp + 64 + l];
  float a2A = p0[2*stp + l], a2B = p0[2*stp + 64 + l];
  float a3A = p0[3*stp + l], a3B = p0[3*stp + 64 + l];

#define WSTEP(pAv, pBv, sidx) { \
    f2 q0 = (f2){(pAv),(pBv)}, q1 = (f2){0.f,0.f}, q2 = (f2){0.f,0.f}, q3 = (f2){0.f,0.f}; \
    _Pragma("unroll") \
    for (int k = 0; k < 32; k += 4){ \
      const float h0 = rdlane(h, k+0); \
      const float h1 = rdlane(h, k+1); \
      const float h2 = rdlane(h, k+2); \
      const float h3 = rdlane(h, k+3); \
      q0 += w2[k+0] * (f2){h0,h0}; \
      q1 += w2[k+1] * (f2){h1,h1}; \
      q2 += w2[k+2] * (f2){h2,h2}; \
      q3 += w2[k+3] * (f2){h3,h3}; \
    } \
    const f2 qs = (q0+q1)+(q2+q3); \
    const float aA = qs.x;                  /* lanes<32: i, lanes>=32: f */ \
    const float aB = qs.y;                  /* lanes<32: g, lanes>=32: o */ \
    const float fga = xswap32(aA, lo32);    /* lanes<32 receive f */ \
    const float oga = xswap32(aB, lo32);    /* lanes<32 receive o */ \
    const float cc = sigm(fga)*cst + sigm(aA)*tanh_(aB);  /* valid lanes<32 */ \
    cst = cc; \
    h = sigm(oga)*tanh_(cc);                               /* valid lanes<32 */ \
    if (lo32) hring[((sidx) & 31)*36 + l] = h; \
  }

  for (int t = 0; t < S_; t += 4){
    float n0A=0.f, n0B=0.f, n1A=0.f, n1B=0.f, n2A=0.f, n2B=0.f, n3A=0.f, n3B=0.f;
    if (t + 4 < S_){                     // issue prefetch for steps t+4..t+7 FIRST
      const float* q = p0 + (ptrdiff_t)(t+4)*stp;
      n0A = q[0*stp + l]; n0B = q[0*stp + 64 + l];
      n1A = q[1*stp + l]; n1B = q[1*stp + 64 + l];
      n2A = q[2*stp + l]; n2B = q[2*stp + 64 + l];
      n3A = q[3*stp + l]; n3B = q[3*stp + 64 + l];
    }
    WSTEP(a0A, a0B, t+0)
    WSTEP(a1A, a1B, t+1)
    WSTEP(a2A, a2B, t+2)
    WSTEP(a3A, a3B, t+3)
    a0A=n0A; a0B=n0B; a1A=n1A; a1B=n1B;
    a2A=n2A; a2B=n2B; a3A=n3A; a3B=n3B;

    if ((t & 31) == 28){                 // flush steps s0..s0+31 coalesced
      const int s0 = t & ~31;
      const int srow = l >> 1, half = l & 1;
      const int s = s0 + srow;
      const int ss = d ? (S_ - 1 - s) : s;
      const float4* src = (const float4*)&hring[srow*36 + half*16];
      float4* dst = (float4*)(LO + ((size_t)n*S_ + ss)*64 + d*32 + half*16);
      dst[0] = src[0]; dst[1] = src[1]; dst[2] = src[2]; dst[3] = src[3];
    }
  }
#undef WSTEP
}

// ---------------- output head: sigmoid(lstm_out @ out_W^T + b) -> f32 ----------------
__global__ void k_out(const float* ws, const float* out_b, float* out){
  const int row = blockIdx.x*blockDim.x + threadIdx.x;
  const float4* lo = (const float4*)(ws + OFF_LO + (size_t)row*64);
  const float* OW = ws + OFF_OW;
  float a0 = out_b[0], a1 = out_b[1];
  #pragma unroll
  for (int q = 0; q < 16; ++q){
    const float4 v = lo[q];
    a0 += OW[q*4+0]*v.x + OW[q*4+1]*v.y + OW[q*4+2]*v.z + OW[q*4+3]*v.w;
    a1 += OW[64+q*4+0]*v.x + OW[64+q*4+1]*v.y + OW[64+q*4+2]*v.z + OW[64+q*4+3]*v.w;
  }
  out[row*2+0] = sigm(a0);
  out[row*2+1] = sigm(a1);
}

extern "C" void kernel_launch(void* const* d_in, const int* in_sizes, int n_in,
                              void* d_out, int out_size, void* d_ws, size_t ws_size,
                              hipStream_t stream){
  (void)in_sizes; (void)n_in; (void)out_size; (void)ws_size;
  const int*   word_ids   = (const int*)  d_in[0];
  const int*   char_ids   = (const int*)  d_in[1];
  const float* word_table = (const float*)d_in[2];
  const float* char_table = (const float*)d_in[3];
  const float* c_Wih_f    = (const float*)d_in[4];
  const float* c_Whh_f    = (const float*)d_in[5];
  const float* c_b_f      = (const float*)d_in[6];
  const float* c_Wih_b    = (const float*)d_in[7];
  const float* c_Whh_b    = (const float*)d_in[8];
  const float* c_b_b      = (const float*)d_in[9];
  const float* gen_W      = (const float*)d_in[10];
  const float* gen_b      = (const float*)d_in[11];
  const float* w_Wih_f    = (const float*)d_in[12];
  const float* w_Whh_f    = (const float*)d_in[13];
  const float* w_b_f      = (const float*)d_in[14];
  const float* w_Wih_b    = (const float*)d_in[15];
  const float* w_Whh_b    = (const float*)d_in[16];
  const float* w_b_b      = (const float*)d_in[17];
  const float* out_W      = (const float*)d_in[18];
  const float* out_b      = (const float*)d_in[19];
  float* ws  = (float*)d_ws;
  float* out = (float*)d_out;

  hipLaunchKernelGGL(k_prep,  dim3(64),   dim3(256), 0, stream,
                     gen_W, w_Wih_f, w_Wih_b, w_Whh_f, w_Whh_b, out_W, ws);
  hipLaunchKernelGGL(k_char,  dim3(1024), dim3(256), 0, stream,
                     char_ids, char_table, c_Wih_f, c_Whh_f, c_b_f,
                     c_Wih_b, c_Whh_b, c_b_b, ws);
  hipLaunchKernelGGL(k_genp,  dim3(BS_/GROWS), dim3(128), 0, stream,
                     word_ids, word_table, gen_b, w_b_f, w_b_b, ws);
  hipLaunchKernelGGL(k_wlstm, dim3(64),   dim3(64),  0, stream,
                     ws + OFF_WHHT, ws + OFF_PRE, ws + OFF_LO);
  hipLaunchKernelGGL(k_out,   dim3(64),   dim3(128), 0, stream, ws, out_b, out);
}

// Round 24
// 170.307 us; speedup vs baseline: 1.0781x; 1.0184x over previous
//
#include <hip/hip_runtime.h>
#include <hip/hip_bf16.h>

#define B_    32
#define S_    256
#define BS_   8192      // B_*S_
#define Wc_   16        // chars per word
#define CDIM_ 16
#define CH_   16
#define WDIM_ 300
#define KX_   332       // WDIM_+2*CH_
#define XC_   336       // padded X row (84 float4)
#define GEN_  100
#define WVP_  104       // padded word_vecs row
#define WH_   32
#define NG_   128       // 4*WH_
#define GROWS 4         // rows per k_genp block (r24: 4 WITH unroll guard — untested cell)

constexpr size_t OFF_WV   = 0;                                   // [8192][104] f32 (unused after fusion)
constexpr size_t OFF_PRE  = OFF_WV   + (size_t)BS_*WVP_;         // [2][256][32][128]
constexpr size_t OFF_LO   = OFF_PRE  + (size_t)2*S_*B_*NG_;      // [8192][64]
constexpr size_t OFF_CHB  = OFF_LO   + (size_t)BS_*64;           // [8192][32] char h
constexpr size_t OFF_GWT  = OFF_CHB  + (size_t)BS_*32;           // [332][128]
constexpr size_t OFF_WIHT = OFF_GWT  + (size_t)KX_*128;          // [2][100][128]
constexpr size_t OFF_WHHT = OFF_WIHT + (size_t)2*GEN_*NG_;       // [2][32][128]
constexpr size_t OFF_OW   = OFF_WHHT + (size_t)2*WH_*NG_;        // [2][64]

typedef __attribute__((ext_vector_type(2))) float f2;
typedef __attribute__((ext_vector_type(2))) unsigned u2;

// native-exp2 activations: v_exp_f32 + v_rcp_f32, ~3 insts vs ~11 for __ocml_expf
__device__ __forceinline__ float sigm(float x){
  return __builtin_amdgcn_rcpf(1.f + __builtin_amdgcn_exp2f(-1.44269504089f*x));
}
__device__ __forceinline__ float tanh_(float x){
  return 1.f - 2.f*__builtin_amdgcn_rcpf(1.f + __builtin_amdgcn_exp2f(2.88539008178f*x));
}
__device__ __forceinline__ float rdlane(float v, int lane){
  return __uint_as_float(__builtin_amdgcn_readlane(__float_as_uint(v), lane));
}
#if defined(__has_builtin) && __has_builtin(__builtin_amdgcn_permlane32_swap)
__device__ __forceinline__ float xswap32(float v, bool lo32){
  u2 r = __builtin_amdgcn_permlane32_swap(__float_as_uint(v), __float_as_uint(v), false, false);
  return __uint_as_float(lo32 ? r.y : r.x);
}
#else
__device__ __forceinline__ float xswap32(float v, bool lo32){
  (void)lo32;
  return __shfl_xor(v, 32);
}
#endif

// ---------------- prep: transpose small weights ----------------
__global__ void k_prep(const float* gen_W, const float* wih_f, const float* wih_b,
                       const float* whh_f, const float* whh_b, const float* out_W,
                       float* ws){
  int idx = blockIdx.x*blockDim.x + threadIdx.x;
  int stride = gridDim.x*blockDim.x;
  for (int i = idx; i < GEN_*KX_; i += stride){       // gen_W [100][332] -> [k][j] stride 128
    int j = i / KX_, k = i - j*KX_;
    ws[OFF_GWT + (size_t)k*128 + j] = gen_W[i];
  }
  for (int i = idx; i < NG_*GEN_; i += stride){       // w_Wih [128][100] -> [k][g]
    int g = i / GEN_, k = i - g*GEN_;
    ws[OFF_WIHT + 0*GEN_*NG_ + (size_t)k*NG_ + g] = wih_f[i];
    ws[OFF_WIHT + 1*GEN_*NG_ + (size_t)k*NG_ + g] = wih_b[i];
  }
  for (int i = idx; i < NG_*WH_; i += stride){        // w_Whh [128][32] -> [k][g]
    int g = i / WH_, k = i - g*WH_;
    ws[OFF_WHHT + 0*WH_*NG_ + (size_t)k*NG_ + g] = whh_f[i];
    ws[OFF_WHHT + 1*WH_*NG_ + (size_t)k*NG_ + g] = whh_b[i];
  }
  for (int i = idx; i < 2*64; i += stride) ws[OFF_OW + i] = out_W[i];
}

// ---------------- char BiLSTM: lane = (seq, unit); 16 lanes/seq ----------------
__global__ void __launch_bounds__(256, 2) k_char(const int* char_ids, const float* char_table,
                       const float* Wih_f, const float* Whh_f, const float* b_f,
                       const float* Wih_b, const float* Whh_b, const float* b_b,
                       float* ws){
  __shared__ float xr[16*324];        // [s][t][k] row stride 20, s stride 324
  __shared__ float occ_pad[4864];     // 19KB: VGPR-budget lever
  const int dir = blockIdx.x & 1;
  const int sg  = blockIdx.x >> 1;
  const int tid = threadIdx.x;
  const float* WI = dir ? Wih_b : Wih_f;
  const float* WH = dir ? Whh_b : Whh_f;
  const float* BB = dir ? b_b  : b_f;
  const int ls = tid >> 4, u = tid & 15;
  const int seq0 = sg * 16;
  {
    const int id = char_ids[(seq0 + ls)*Wc_ + u];
    const float4* sr = (const float4*)(char_table + (size_t)id*CDIM_);
    float4 v0 = sr[0], v1 = sr[1], v2 = sr[2], v3 = sr[3];
    float* xw = &xr[ls*324 + u*20];
    *(float4*)(xw+0)  = v0; *(float4*)(xw+4)  = v1;
    *(float4*)(xw+8)  = v2; *(float4*)(xw+12) = v3;
    if (__builtin_expect(id == 0x7fffffff, 0)) occ_pad[tid] = v0.x;  // unprovable-dead
  }
  float wi[4][16];
  #pragma unroll
  for (int g = 0; g < 4; ++g){
    const float4* wr = (const float4*)(WI + (size_t)(g*16+u)*CDIM_);
    float4 a = wr[0], b = wr[1], c = wr[2], d = wr[3];
    wi[g][0]=a.x; wi[g][1]=a.y; wi[g][2]=a.z; wi[g][3]=a.w;
    wi[g][4]=b.x; wi[g][5]=b.y; wi[g][6]=b.z; wi[g][7]=b.w;
    wi[g][8]=c.x; wi[g][9]=c.y; wi[g][10]=c.z; wi[g][11]=c.w;
    wi[g][12]=d.x; wi[g][13]=d.y; wi[g][14]=d.z; wi[g][15]=d.w;
  }
  float bias[4];
  #pragma unroll
  for (int g = 0; g < 4; ++g) bias[g] = BB[g*16+u];
  __syncthreads();
  float xp[16][4];
  const float* xb = &xr[ls*324];
  #pragma unroll
  for (int p = 0; p < 16; ++p){
    const int tm = dir ? (15-p) : p;
    const float4 x0 = *(const float4*)(xb + tm*20 + 0);
    const float4 x1 = *(const float4*)(xb + tm*20 + 4);
    const float4 x2 = *(const float4*)(xb + tm*20 + 8);
    const float4 x3 = *(const float4*)(xb + tm*20 + 12);
    float xk[16] = {x0.x,x0.y,x0.z,x0.w, x1.x,x1.y,x1.z,x1.w,
                    x2.x,x2.y,x2.z,x2.w, x3.x,x3.y,x3.z,x3.w};
    #pragma unroll
    for (int g = 0; g < 4; ++g){
      float a0 = bias[g], a1 = 0.f;
      #pragma unroll
      for (int k = 0; k < 16; k += 2){ a0 += wi[g][k]*xk[k]; a1 += wi[g][k+1]*xk[k+1]; }
      xp[p][g] = a0 + a1;
    }
  }
  float wh[4][16];
  #pragma unroll
  for (int g = 0; g < 4; ++g){
    const float4* wr = (const float4*)(WH + (size_t)(g*16+u)*CH_);
    float4 a = wr[0], b = wr[1], c = wr[2], d = wr[3];
    wh[g][0]=a.x; wh[g][1]=a.y; wh[g][2]=a.z; wh[g][3]=a.w;
    wh[g][4]=b.x; wh[g][5]=b.y; wh[g][6]=b.z; wh[g][7]=b.w;
    wh[g][8]=c.x; wh[g][9]=c.y; wh[g][10]=c.z; wh[g][11]=c.w;
    wh[g][12]=d.x; wh[g][13]=d.y; wh[g][14]=d.z; wh[g][15]=d.w;
  }
  const int lbase = (tid & 63) & 48;
  float h = 0.f, c = 0.f;
  #pragma unroll
  for (int p = 0; p < 16; ++p){
    float ai = xp[p][0], af = xp[p][1], ag = xp[p][2], ao = xp[p][3];
    #pragma unroll
    for (int k = 0; k < 16; ++k){
      const float hk = __shfl(h, lbase + k, 64);
      ai += wh[0][k]*hk; af += wh[1][k]*hk;
      ag += wh[2][k]*hk; ao += wh[3][k]*hk;
    }
    c = sigm(af)*c + sigm(ai)*tanh_(ag);
    h = sigm(ao)*tanh_(c);
  }
  ws[OFF_CHB + (size_t)(seq0 + ls)*32 + dir*16 + u] = h;
}

// ---------------- fused gen + word-LSTM input projection ----------------
// r24: GROWS=4 WITH the unroll(disable) guard — the untested grid cell.
// r20's GROWS=4 explosion (VGPR 256, 206MB spill) was WITHOUT the guard;
// r21 proved the guard at GROWS=8 (69us, +15% vs GROWS=16). 2048 blocks =
// 8 blocks/CU = 4 waves/SIMD — next TLP doubling for the latency stall.
__global__ void __launch_bounds__(128) k_genp(const int* word_ids, const float* word_table, const float* gen_b,
                       const float* wb_f, const float* wb_b, float* ws){
  __shared__ __align__(16) float xt[GROWS*XC_];    // 5.4 KB
  __shared__ __align__(16) float wvs[GROWS*WVP_];  // 1.7 KB
  __shared__ int wids[GROWS];
  const int r0 = blockIdx.x*GROWS;
  if (threadIdx.x < GROWS) wids[threadIdx.x] = word_ids[r0 + threadIdx.x];
  __syncthreads();
  float4* xt4 = (float4*)xt;
  for (int i = threadIdx.x; i < GROWS*75; i += 128){       // word part: 75 float4/row
    const int r = i/75, q = i - r*75;
    xt4[r*84 + q] = ((const float4*)(word_table + (size_t)wids[r]*WDIM_))[q];
  }
  for (int i = threadIdx.x; i < GROWS*8; i += 128){        // char part: 8 float4/row
    const int r = i >> 3, q = i & 7;
    xt4[r*84 + 75 + q] = ((const float4*)(ws + OFF_CHB + (size_t)(r0+r)*32))[q];
  }
  __syncthreads();
  const int j = threadIdx.x;                   // j<100 valid
  const float bj = (j < GEN_) ? gen_b[j] : 0.f;
  float acc[GROWS];
  #pragma unroll
  for (int r = 0; r < GROWS; ++r) acc[r] = bj;
  const float* WT = ws + OFF_GWT;
  #pragma clang loop unroll(disable)
  for (int k4 = 0; k4 < KX_/4; ++k4){
    const int k = k4*4;
    const float w0 = WT[(size_t)(k+0)*128 + j];
    const float w1 = WT[(size_t)(k+1)*128 + j];
    const float w2 = WT[(size_t)(k+2)*128 + j];
    const float w3 = WT[(size_t)(k+3)*128 + j];
    #pragma unroll
    for (int r = 0; r < GROWS; ++r){
      const float4 xv = xt4[r*84 + k4];
      acc[r] += w0*xv.x + w1*xv.y + w2*xv.z + w3*xv.w;
    }
  }
  if (j < GEN_){
    #pragma unroll
    for (int r = 0; r < GROWS; ++r){
      const float a = acc[r];
      wvs[r*WVP_ + j] = 0.5f*a*(1.f + erff(a*0.70710678118f));
    }
  }
  __syncthreads();
  // phase 2: pre-activation projection for both directions
  const int g = threadIdx.x;                   // all 128 valid
  for (int d = 0; d < 2; ++d){
    const float* W2 = ws + OFF_WIHT + (size_t)d*GEN_*NG_;
    const float wb = (d ? wb_b : wb_f)[g];
    float ac2[GROWS];
    #pragma unroll
    for (int r = 0; r < GROWS; ++r) ac2[r] = wb;
    #pragma clang loop unroll(disable)
    for (int k4 = 0; k4 < GEN_/4; ++k4){
      const int k = k4*4;
      const float w0 = W2[(size_t)(k+0)*NG_ + g];
      const float w1 = W2[(size_t)(k+1)*NG_ + g];
      const float w2 = W2[(size_t)(k+2)*NG_ + g];
      const float w3 = W2[(size_t)(k+3)*NG_ + g];
      #pragma unroll
      for (int r = 0; r < GROWS; ++r){
        const float4 xv = *(const float4*)&wvs[r*WVP_ + k];
        ac2[r] += w0*xv.x + w1*xv.y + w2*xv.z + w3*xv.w;
      }
    }
    float* pre = ws + OFF_PRE + (size_t)d*S_*B_*NG_;
    #pragma unroll
    for (int r = 0; r < GROWS; ++r){
      const int row = r0 + r, bb = row >> 8, ss = row & 255;
      pre[((size_t)ss*B_ + bb)*NG_ + g] = ac2[r];
    }
  }
}

// ---------------- word BiLSTM scan: 1 wave per (dir, batch row), packed FMAs ----------------
// (best: 81.4us, VGPR 88 — unchanged; locked config)
#define BN_ ((size_t)B_*NG_)
__global__ void __launch_bounds__(64) k_wlstm(const float* __restrict__ WHT,
                                              const float* __restrict__ PRE,
                                              float* __restrict__ LO){
  __shared__ __align__(16) float hring[5632];   // [32][36] used; size = VGPR-budget lever (r12)
  const int pair = blockIdx.x;          // 0..63
  const int d = pair >> 5;
  const int n = pair & 31;
  const int l = threadIdx.x;
  const bool lo32 = (l < 32);
  const float* WT = WHT + (size_t)d*WH_*NG_;
  f2 w2[32];                            // (wA[k], wB[k]) — gates l and 64+l
  #pragma unroll
  for (int k = 0; k < 32; ++k){
    w2[k] = (f2){ WT[(size_t)k*NG_ + l], WT[(size_t)k*NG_ + 64 + l] };
  }
  const float* pre = PRE + (size_t)d*S_*BN_ + (size_t)n*NG_;
  const float* p0 = pre + (size_t)(d ? (S_-1) : 0)*BN_;
  const ptrdiff_t stp = (d ? -1 : 1) * (ptrdiff_t)BN_;
  float cst = 0.f, h = 0.f;

  // prefetch steps 0..3
  float a0A = p0[0*stp + l], a0B = p0[0*stp + 64 + l];
  float a1A = p0[1*stp + l], a1B = p0[1*stp + 64 + l];
  float a2A = p0[2*stp + l], a2B = p0[2*stp + 64 + l];
  float a3A = p0[3*stp + l], a3B = p0[3*stp + 64 + l];

#define WSTEP(pAv, pBv, sidx) { \
    f2 q0 = (f2){(pAv),(pBv)}, q1 = (f2){0.f,0.f}, q2 = (f2){0.f,0.f}, q3 = (f2){0.f,0.f}; \
    _Pragma("unroll") \
    for (int k = 0; k < 32; k += 4){ \
      const float h0 = rdlane(h, k+0); \
      const float h1 = rdlane(h, k+1); \
      const float h2 = rdlane(h, k+2); \
      const float h3 = rdlane(h, k+3); \
      q0 += w2[k+0] * (f2){h0,h0}; \
      q1 += w2[k+1] * (f2){h1,h1}; \
      q2 += w2[k+2] * (f2){h2,h2}; \
      q3 += w2[k+3] * (f2){h3,h3}; \
    } \
    const f2 qs = (q0+q1)+(q2+q3); \
    const float aA = qs.x;                  /* lanes<32: i, lanes>=32: f */ \
    const float aB = qs.y;                  /* lanes<32: g, lanes>=32: o */ \
    const float fga = xswap32(aA, lo32);    /* lanes<32 receive f */ \
    const float oga = xswap32(aB, lo32);    /* lanes<32 receive o */ \
    const float cc = sigm(fga)*cst + sigm(aA)*tanh_(aB);  /* valid lanes<32 */ \
    cst = cc; \
    h = sigm(oga)*tanh_(cc);                               /* valid lanes<32 */ \
    if (lo32) hring[((sidx) & 31)*36 + l] = h; \
  }

  for (int t = 0; t < S_; t += 4){
    float n0A=0.f, n0B=0.f, n1A=0.f, n1B=0.f, n2A=0.f, n2B=0.f, n3A=0.f, n3B=0.f;
    if (t + 4 < S_){                     // issue prefetch for steps t+4..t+7 FIRST
      const float* q = p0 + (ptrdiff_t)(t+4)*stp;
      n0A = q[0*stp + l]; n0B = q[0*stp + 64 + l];
      n1A = q[1*stp + l]; n1B = q[1*stp + 64 + l];
      n2A = q[2*stp + l]; n2B = q[2*stp + 64 + l];
      n3A = q[3*stp + l]; n3B = q[3*stp + 64 + l];
    }
    WSTEP(a0A, a0B, t+0)
    WSTEP(a1A, a1B, t+1)
    WSTEP(a2A, a2B, t+2)
    WSTEP(a3A, a3B, t+3)
    a0A=n0A; a0B=n0B; a1A=n1A; a1B=n1B;
    a2A=n2A; a2B=n2B; a3A=n3A; a3B=n3B;

    if ((t & 31) == 28){                 // flush steps s0..s0+31 coalesced
      const int s0 = t & ~31;
      const int srow = l >> 1, half = l & 1;
      const int s = s0 + srow;
      const int ss = d ? (S_ - 1 - s) : s;
      const float4* src = (const float4*)&hring[srow*36 + half*16];
      float4* dst = (float4*)(LO + ((size_t)n*S_ + ss)*64 + d*32 + half*16);
      dst[0] = src[0]; dst[1] = src[1]; dst[2] = src[2]; dst[3] = src[3];
    }
  }
#undef WSTEP
}

// ---------------- output head: sigmoid(lstm_out @ out_W^T + b) -> f32 ----------------
__global__ void k_out(const float* ws, const float* out_b, float* out){
  const int row = blockIdx.x*blockDim.x + threadIdx.x;
  const float4* lo = (const float4*)(ws + OFF_LO + (size_t)row*64);
  const float* OW = ws + OFF_OW;
  float a0 = out_b[0], a1 = out_b[1];
  #pragma unroll
  for (int q = 0; q < 16; ++q){
    const float4 v = lo[q];
    a0 += OW[q*4+0]*v.x + OW[q*4+1]*v.y + OW[q*4+2]*v.z + OW[q*4+3]*v.w;
    a1 += OW[64+q*4+0]*v.x + OW[64+q*4+1]*v.y + OW[64+q*4+2]*v.z + OW[64+q*4+3]*v.w;
  }
  out[row*2+0] = sigm(a0);
  out[row*2+1] = sigm(a1);
}

extern "C" void kernel_launch(void* const* d_in, const int* in_sizes, int n_in,
                              void* d_out, int out_size, void* d_ws, size_t ws_size,
                              hipStream_t stream){
  (void)in_sizes; (void)n_in; (void)out_size; (void)ws_size;
  const int*   word_ids   = (const int*)  d_in[0];
  const int*   char_ids   = (const int*)  d_in[1];
  const float* word_table = (const float*)d_in[2];
  const float* char_table = (const float*)d_in[3];
  const float* c_Wih_f    = (const float*)d_in[4];
  const float* c_Whh_f    = (const float*)d_in[5];
  const float* c_b_f      = (const float*)d_in[6];
  const float* c_Wih_b    = (const float*)d_in[7];
  const float* c_Whh_b    = (const float*)d_in[8];
  const float* c_b_b      = (const float*)d_in[9];
  const float* gen_W      = (const float*)d_in[10];
  const float* gen_b      = (const float*)d_in[11];
  const float* w_Wih_f    = (const float*)d_in[12];
  const float* w_Whh_f    = (const float*)d_in[13];
  const float* w_b_f      = (const float*)d_in[14];
  const float* w_Wih_b    = (const float*)d_in[15];
  const float* w_Whh_b    = (const float*)d_in[16];
  const float* w_b_b      = (const float*)d_in[17];
  const float* out_W      = (const float*)d_in[18];
  const float* out_b      = (const float*)d_in[19];
  float* ws  = (float*)d_ws;
  float* out = (float*)d_out;

  hipLaunchKernelGGL(k_prep,  dim3(64),   dim3(256), 0, stream,
                     gen_W, w_Wih_f, w_Wih_b, w_Whh_f, w_Whh_b, out_W, ws);
  hipLaunchKernelGGL(k_char,  dim3(1024), dim3(256), 0, stream,
                     char_ids, char_table, c_Wih_f, c_Whh_f, c_b_f,
                     c_Wih_b, c_Whh_b, c_b_b, ws);
  hipLaunchKernelGGL(k_genp,  dim3(BS_/GROWS), dim3(128), 0, stream,
                     word_ids, word_table, gen_b, w_b_f, w_b_b, ws);
  hipLaunchKernelGGL(k_wlstm, dim3(64),   dim3(64),  0, stream,
                     ws + OFF_WHHT, ws + OFF_PRE, ws + OFF_LO);
  hipLaunchKernelGGL(k_out,   dim3(64),   dim3(128), 0, stream, ws, out_b, out);
}